// Round 1
// baseline (746.724 us; speedup 1.0000x reference)
//
#include <hip/hip_runtime.h>

// Mamba2 quantized decode step, MI355X/gfx950. Round 6.
// Structural change vs R5: fuse the 5 dependent stages after quantx into ONE
// persistent kernel (512 blocks x 512 threads, 2 blocks/CU guaranteed by
// __launch_bounds__(512,4): VGPR<=128 -> 16 waves/CU, LDS 33.1KB -> 2/CU,
// grid = 2 x 256 CUs) with manual device-scope grid barriers. 6 dispatches -> 2.
// Barrier state re-initialized by quantx each iteration (workspace is poisoned).
// Numerics identical to R5 (same quant math, same MFMA fragment layouts).

#define B_       64
#define DMODEL   2048
#define DSSM     4096
#define NH       64
#define HD       64
#define DSTATE   128
#define DPROJ    8512
#define XBCLEN   4352   // DSSM + 2*DSTATE
#define NBLK     512
#define NTHR     512
#define LSTRIDE1 (DMODEL / 4 + 4)   // 516 uints, pad vs bank conflicts
#define LSTRIDE2 (DSSM / 4 + 4)     // 1028 uints

typedef __attribute__((ext_vector_type(4))) int int4v;

__device__ __forceinline__ float absmax4(float4 v) {
  return fmaxf(fmaxf(fabsf(v.x), fabsf(v.y)), fmaxf(fabsf(v.z), fabsf(v.w)));
}

__device__ __forceinline__ unsigned int pack4(float a, float b, float c, float d,
                                              float rs) {
  int c0 = (int)rintf(a * rs), c1 = (int)rintf(b * rs);
  int c2 = (int)rintf(c * rs), c3 = (int)rintf(d * rs);
  return (unsigned)(c0 & 255) | ((unsigned)(c1 & 255) << 8) |
         ((unsigned)(c2 & 255) << 16) | ((unsigned)(c3 & 255) << 24);
}

__device__ __forceinline__ float waveMax(float v) {
  #pragma unroll
  for (int off = 32; off > 0; off >>= 1)
    v = fmaxf(v, __shfl_xor(v, off, 64));
  return v;
}

// block-wide max for 512-thread blocks (8 waves)
__device__ __forceinline__ float blockMax512(float v, float* sm) {
  v = waveMax(v);
  __syncthreads();
  if ((threadIdx.x & 63) == 0) sm[threadIdx.x >> 6] = v;
  __syncthreads();
  float m = sm[0];
  #pragma unroll
  for (int i = 1; i < 8; i++) m = fmaxf(m, sm[i]);
  return m;
}

// device-scope grid barrier; bar[0]=arrive count, bar[1]=generation.
// Safe because all NBLK blocks are co-resident (occupancy pinned by
// __launch_bounds__ + static LDS; grid = 2 x 256 CUs, the sanctioned pattern).
__device__ __forceinline__ void gridbar(unsigned* bar) {
  __syncthreads();
  if (threadIdx.x == 0) {
    __threadfence();
    unsigned* cnt = bar;
    unsigned* gen = bar + 1;
    unsigned g = __hip_atomic_load(gen, __ATOMIC_RELAXED, __HIP_MEMORY_SCOPE_AGENT);
    unsigned a = __hip_atomic_fetch_add(cnt, 1u, __ATOMIC_ACQ_REL,
                                        __HIP_MEMORY_SCOPE_AGENT);
    if (a == NBLK - 1) {
      __hip_atomic_store(cnt, 0u, __ATOMIC_RELAXED, __HIP_MEMORY_SCOPE_AGENT);
      __hip_atomic_store(gen, g + 1u, __ATOMIC_RELEASE, __HIP_MEMORY_SCOPE_AGENT);
    } else {
      while (__hip_atomic_load(gen, __ATOMIC_ACQUIRE, __HIP_MEMORY_SCOPE_AGENT) == g)
        __builtin_amdgcn_s_sleep(8);
    }
    __threadfence();
  }
  __syncthreads();
}

// ---------- dispatch 1: quantize hidden (64 x 2048) -> int8, init barrier ----
__global__ __launch_bounds__(256) void quantx(const float* __restrict__ in,
                                              unsigned int* __restrict__ outq,
                                              float* __restrict__ scales,
                                              unsigned* __restrict__ bar) {
  __shared__ float sm[4];
  int r = blockIdx.x;
  const float4* row = (const float4*)(in + (size_t)r * DMODEL);
  float4 v[2];
  float m = 0.f;
  #pragma unroll
  for (int i = 0; i < 2; i++) {
    v[i] = row[threadIdx.x + i * 256];
    m = fmaxf(m, absmax4(v[i]));
  }
  m = waveMax(m);
  __syncthreads();
  if ((threadIdx.x & 63) == 0) sm[threadIdx.x >> 6] = m;
  __syncthreads();
  float mx = fmaxf(fmaxf(sm[0], sm[1]), fmaxf(sm[2], sm[3]));
  float s = mx * (1.0f / 127.0f);
  float rs = (s == 0.f) ? 0.f : 127.0f / mx;
  if (s == 0.f) s = 1.f;
  if (threadIdx.x == 0) scales[r] = s;
  unsigned int* orow = outq + (size_t)r * (DMODEL / 4);
  #pragma unroll
  for (int i = 0; i < 2; i++)
    orow[threadIdx.x + i * 256] = pack4(v[i].x, v[i].y, v[i].z, v[i].w, rs);
  if (r == 0 && threadIdx.x == 0) { bar[0] = 0u; bar[1] = 0u; }
}

// ---------- dispatch 2: fused pipeline ----------
__global__ __launch_bounds__(NTHR, 4) void mega(
    const float* __restrict__ W_in, const char* __restrict__ Aq,
    const float* __restrict__ sA, float* __restrict__ zxb,
    const float* __restrict__ dt_bias, const float* __restrict__ A_log,
    float* __restrict__ zbuf, float* __restrict__ xbcq,
    float* __restrict__ coefs, const float* __restrict__ ssm,
    float* __restrict__ yraw, const float* __restrict__ Dv,
    unsigned int* __restrict__ q3, float* __restrict__ sy,
    const float* __restrict__ W_out, float* __restrict__ out,
    unsigned* __restrict__ bar) {
  __shared__ union {
    struct { unsigned int wq[16 * LSTRIDE1]; float smax[16]; } g1;   // 33,088 B
    struct { unsigned int wq[4 * LSTRIDE2]; float smax[4]; float hmax[4][2]; } g2;
    struct { float dts[NH]; float sm[8]; float sbc; } mid;
    float sm[8];
  } S;

  int t = threadIdx.x, wave = t >> 6, lane = t & 63;
  int bid = blockIdx.x;
  int l16 = lane & 15, quad = lane >> 4;

  // ================= phase 1: fused quant+GEMM1 (zxb = x @ W_in^T) ==========
  for (int tile = bid; tile < DPROJ / 16; tile += NBLK) {
    int n0 = tile * 16;
    // quant 2 weight rows per wave (8 waves x 2 = 16 rows), fp32 read ONCE
    #pragma unroll
    for (int rr = 0; rr < 2; rr++) {
      int row = wave * 2 + rr;
      const float4* rp = (const float4*)(W_in + (size_t)(n0 + row) * DMODEL);
      float4 v[8];
      float m = 0.f;
      #pragma unroll
      for (int c = 0; c < 8; c++) {
        v[c] = rp[lane + c * 64];
        m = fmaxf(m, absmax4(v[c]));
      }
      m = waveMax(m);
      float s = (m == 0.f) ? 1.f : m * (1.0f / 127.0f);
      float rs = (m == 0.f) ? 0.f : 127.0f / m;
      if (lane == 0) S.g1.smax[row] = s;
      unsigned int* wrow = S.g1.wq + row * LSTRIDE1;
      #pragma unroll
      for (int c = 0; c < 8; c++)
        wrow[lane + c * 64] = pack4(v[c].x, v[c].y, v[c].z, v[c].w, rs);
    }
    __syncthreads();
    // MFMA: wave = (m-tile 0..3, n-half 0..1); C/D: col=lane&15, row=quad*4+reg
    int m4 = wave >> 1, nh = wave & 1;
    int4v acc = {0, 0, 0, 0};
    const char* arow = Aq + (size_t)(m4 * 16 + l16) * DMODEL + quad * 16;
    const unsigned int* brow = S.g1.wq + (nh * 8 + l16) * LSTRIDE1 + quad * 4;
    for (int k = 0; k < DMODEL; k += 256) {
      int4v af[4], bf[4];
      #pragma unroll
      for (int u = 0; u < 4; u++)
        af[u] = *(const int4v*)(arow + k + u * 64);
      #pragma unroll
      for (int u = 0; u < 4; u++) {
        int4v z = {0, 0, 0, 0};
        bf[u] = z;
        if (l16 < 8) bf[u] = *(const int4v*)(brow + (k + u * 64) / 4);
      }
      #pragma unroll
      for (int u = 0; u < 4; u++)
        acc = __builtin_amdgcn_mfma_i32_16x16x64_i8(af[u], bf[u], acc, 0, 0, 0);
    }
    if (l16 < 8) {
      float sw = S.g1.smax[nh * 8 + l16];
      #pragma unroll
      for (int r = 0; r < 4; r++) {
        int mr = m4 * 16 + quad * 4 + r;
        zxb[(size_t)mr * DPROJ + n0 + nh * 8 + l16] = (float)acc[r] * sA[mr] * sw;
      }
    }
    __syncthreads();   // wq reused by next tile
  }
  gridbar(bar);

  // ================= phase 2: kmid (split z/xBC/dt, quant xBC, coefs) =======
  if (bid < B_) {
    int b = bid;
    float4 v[5];
    float m = 0.f;
    float4 q8 = {0.f, 0.f, 0.f, 0.f};
    #pragma unroll
    for (int i = 0; i < 5; i++) {
      int idx = t + i * 512;
      if (idx < 2128) {
        float4 a = ((const float4*)(zxb + (size_t)b * DPROJ))[idx];
        v[i] = a;
        if (idx >= 1024 && idx < 2112) m = fmaxf(m, absmax4(a));
        if (idx >= 2112) {                 // dt segment: i==4, t in [64,80)
          S.mid.dts[(idx - 2112) * 4 + 0] = a.x;
          S.mid.dts[(idx - 2112) * 4 + 1] = a.y;
          S.mid.dts[(idx - 2112) * 4 + 2] = a.z;
          S.mid.dts[(idx - 2112) * 4 + 3] = a.w;
        }
      }
    }
    float mx = blockMax512(m, S.mid.sm);   // barrier also publishes dts[]
    float s = mx * (1.0f / 127.0f);
    float rs = (s == 0.f) ? 0.f : 127.0f / mx;
    if (s == 0.f) s = 1.f;
    #pragma unroll
    for (int i = 0; i < 5; i++) {
      int idx = t + i * 512;
      if (idx < 1024) {
        ((float4*)(zbuf + (size_t)b * DSSM))[idx] = v[i];
      } else if (idx < 2112) {
        float4 q;
        q.x = rintf(v[i].x * rs) * s;
        q.y = rintf(v[i].y * rs) * s;
        q.z = rintf(v[i].z * rs) * s;
        q.w = rintf(v[i].w * rs) * s;
        if (i == 4 && t < 64) q8 = q;      // B/C f4s live at idx 2048..2111
        ((float4*)(xbcq + (size_t)b * XBCLEN))[idx - 1024] = q;
      }
    }
    // B.C from quantized values (wave 0: lanes 0..31 = B, 32..63 = C)
    float4 oth;
    oth.x = __shfl(q8.x, lane ^ 32, 64);
    oth.y = __shfl(q8.y, lane ^ 32, 64);
    oth.z = __shfl(q8.z, lane ^ 32, 64);
    oth.w = __shfl(q8.w, lane ^ 32, 64);
    float p = 0.f;
    if (t < 32) p = q8.x * oth.x + q8.y * oth.y + q8.z * oth.z + q8.w * oth.w;
    #pragma unroll
    for (int off = 1; off < 32; off <<= 1) p += __shfl_xor(p, off, 64);
    if (t == 0) S.mid.sbc = p;
    __syncthreads();
    if (t < NH) {
      float dtv = S.mid.dts[t] + dt_bias[t];
      if (dtv < -2.f) dtv = 0.f;
      else if (dtv <= 2.f)
        dtv = 0.6931471805599453f + 0.5f * dtv + dtv * dtv * (1.f / 8.f)
              + dtv * dtv * dtv * (1.f / 48.f);
      float A = -expf(A_log[t]);
      float dA = fmaxf(dtv * A, -10000.f);
      float e = 1.f + dA + dA * dA * (1.f / 2.f) + dA * dA * dA * (1.f / 6.f)
                + dA * dA * dA * dA * (1.f / 24.f)
                + dA * dA * dA * dA * dA * (1.f / 120.f);
      e = fminf(fmaxf(e, 0.f), 1.f);
      coefs[((size_t)b * NH + t) * 2 + 0] = e;
      coefs[((size_t)b * NH + t) * 2 + 1] = dtv * S.mid.sbc;
    }
  }
  gridbar(bar);

  // ================= phase 3: SSM contraction (8 jobs/block, exact) =========
  {
    int half = t >> 8, th = t & 255;
    #pragma unroll
    for (int jj = 0; jj < 4; jj++) {
      int job = bid * 8 + half * 4 + jj;      // 512*8 = 4096 = B_*NH
      int b = job >> 6, h = job & 63;
      const float* xrow = xbcq + (size_t)b * XBCLEN;
      float4 c4 = *(const float4*)(xrow + DSSM + DSTATE + (th & 31) * 4);
      float2 cf = *(const float2*)(coefs + ((size_t)b * NH + h) * 2);
      const float4* st = (const float4*)(ssm + ((size_t)b * NH + h) * (HD * DSTATE));
      #pragma unroll
      for (int j = 0; j < 8; j++) {
        float4 s4 = st[j * 256 + th];
        float acc = s4.x * c4.x + s4.y * c4.y + s4.z * c4.z + s4.w * c4.w;
        #pragma unroll
        for (int off = 1; off < 32; off <<= 1) acc += __shfl_xor(acc, off, 64);
        if ((th & 31) == 0) {
          int r = j * 8 + (th >> 5);
          int d = h * HD + r;
          yraw[(size_t)b * DSSM + d] = cf.x * acc + cf.y * xrow[d];
        }
      }
    }
  }
  gridbar(bar);

  // ================= phase 4: epilogue fq -> +D*x -> *relu(z) -> fq =========
  if (bid < B_) {
    int b = bid;
    const float* yrow = yraw + (size_t)b * DSSM;
    float4 yv[2];
    float m = 0.f;
    #pragma unroll
    for (int i = 0; i < 2; i++) {
      yv[i] = ((const float4*)yrow)[t + i * 512];
      m = fmaxf(m, absmax4(yv[i]));
    }
    float mx1 = blockMax512(m, S.sm);
    float s1 = mx1 * (1.0f / 127.0f);
    float rs1 = (s1 == 0.f) ? 0.f : 127.0f / mx1;
    if (s1 == 0.f) s1 = 1.f;
    float4 y3[2];
    float m2 = 0.f;
    #pragma unroll
    for (int i = 0; i < 2; i++) {
      int idx = t + i * 512;
      float4 x4 = ((const float4*)(xbcq + (size_t)b * XBCLEN))[idx];
      float4 z4 = ((const float4*)(zbuf + (size_t)b * DSSM))[idx];
      float4 d4 = ((const float4*)Dv)[idx];
      float4 r;
      r.x = (rintf(yv[i].x * rs1) * s1 + d4.x * x4.x) * fmaxf(z4.x, 0.f);
      r.y = (rintf(yv[i].y * rs1) * s1 + d4.y * x4.y) * fmaxf(z4.y, 0.f);
      r.z = (rintf(yv[i].z * rs1) * s1 + d4.z * x4.z) * fmaxf(z4.z, 0.f);
      r.w = (rintf(yv[i].w * rs1) * s1 + d4.w * x4.w) * fmaxf(z4.w, 0.f);
      y3[i] = r;
      m2 = fmaxf(m2, absmax4(r));
    }
    float mx3 = blockMax512(m2, S.sm);
    float s3 = mx3 * (1.0f / 127.0f);
    float rs3 = (s3 == 0.f) ? 0.f : 127.0f / mx3;
    if (s3 == 0.f) s3 = 1.f;
    if (t == 0) sy[b] = s3;
    unsigned int* orow = q3 + (size_t)b * (DSSM / 4);
    #pragma unroll
    for (int i = 0; i < 2; i++)
      orow[t + i * 512] = pack4(y3[i].x, y3[i].y, y3[i].z, y3[i].w, rs3);
  }
  gridbar(bar);

  // ================= phase 5: fused quant+GEMM2 -> out (512 tiles, 1/block) ==
  {
    int n0 = bid * 4;
    // quant 4 weight rows; 2 waves per row, each does half of K=4096
    {
      int row = wave >> 1, kh = wave & 1;
      const float4* rp = (const float4*)(W_out + (size_t)(n0 + row) * DSSM);
      float4 v[8];
      float m = 0.f;
      #pragma unroll
      for (int c = 0; c < 8; c++) {
        v[c] = rp[lane + (kh * 8 + c) * 64];
        m = fmaxf(m, absmax4(v[c]));
      }
      m = waveMax(m);
      if (lane == 0) S.g2.hmax[row][kh] = m;
      __syncthreads();
      float mm = fmaxf(S.g2.hmax[row][0], S.g2.hmax[row][1]);
      float s = (mm == 0.f) ? 1.f : mm * (1.0f / 127.0f);
      float rs = (mm == 0.f) ? 0.f : 127.0f / mm;
      if (lane == 0 && kh == 0) S.g2.smax[row] = s;
      unsigned int* wrow = S.g2.wq + row * LSTRIDE2;
      #pragma unroll
      for (int c = 0; c < 8; c++)
        wrow[lane + (kh * 8 + c) * 64] = pack4(v[c].x, v[c].y, v[c].z, v[c].w, rs);
    }
    __syncthreads();
    if (wave < 4) {
      int m4 = wave;
      int4v acc = {0, 0, 0, 0};
      const char* arow = (const char*)q3 + (size_t)(m4 * 16 + l16) * DSSM + quad * 16;
      const unsigned int* brow = S.g2.wq + l16 * LSTRIDE2 + quad * 4;
      for (int k = 0; k < DSSM; k += 256) {
        int4v af[4], bf[4];
        #pragma unroll
        for (int u = 0; u < 4; u++)
          af[u] = *(const int4v*)(arow + k + u * 64);
        #pragma unroll
        for (int u = 0; u < 4; u++) {
          int4v z = {0, 0, 0, 0};
          bf[u] = z;
          if (l16 < 4) bf[u] = *(const int4v*)(brow + (k + u * 64) / 4);
        }
        #pragma unroll
        for (int u = 0; u < 4; u++)
          acc = __builtin_amdgcn_mfma_i32_16x16x64_i8(af[u], bf[u], acc, 0, 0, 0);
      }
      if (l16 < 4) {
        float sw = S.g2.smax[l16];
        #pragma unroll
        for (int r = 0; r < 4; r++) {
          int mr = m4 * 16 + quad * 4 + r;
          out[(size_t)mr * DMODEL + n0 + l16] = (float)acc[r] * sy[mr] * sw;
        }
      }
    }
  }
}

extern "C" void kernel_launch(void* const* d_in, const int* in_sizes, int n_in,
                              void* d_out, int out_size, void* d_ws, size_t ws_size,
                              hipStream_t stream) {
  const float* hidden  = (const float*)d_in[0];
  const float* ssm     = (const float*)d_in[1];
  const float* W_in    = (const float*)d_in[2];
  const float* dt_bias = (const float*)d_in[3];
  const float* A_log   = (const float*)d_in[4];
  const float* Dv      = (const float*)d_in[5];
  const float* W_out   = (const float*)d_in[6];
  float* out = (float*)d_out;

  char* p = (char*)d_ws;
  auto alloc = [&](size_t bytes) {
    char* r = p;
    p += (bytes + 255) & ~(size_t)255;
    return r;
  };
  unsigned int* xq = (unsigned int*)alloc((size_t)B_ * DMODEL);
  unsigned int* q3 = (unsigned int*)alloc((size_t)B_ * DSSM);
  float* sx    = (float*)alloc(B_ * 4);
  float* sy    = (float*)alloc(B_ * 4);
  float* zxb   = (float*)alloc((size_t)B_ * DPROJ * 4);
  float* zbuf  = (float*)alloc((size_t)B_ * DSSM * 4);
  float* xbcq  = (float*)alloc((size_t)B_ * XBCLEN * 4);
  float* coefs = (float*)alloc((size_t)B_ * NH * 2 * 4);
  float* yraw  = (float*)alloc((size_t)B_ * DSSM * 4);
  unsigned* bar = (unsigned*)alloc(256);

  quantx<<<B_, 256, 0, stream>>>(hidden, xq, sx, bar);
  mega<<<NBLK, NTHR, 0, stream>>>(W_in, (const char*)xq, sx, zxb, dt_bias, A_log,
                                  zbuf, xbcq, coefs, ssm, yraw, Dv, q3, sy,
                                  W_out, out, bar);
}

// Round 2
// 503.645 us; speedup vs baseline: 1.4826x; 1.4826x over previous
//
#include <hip/hip_runtime.h>

// Mamba2 quantized decode step, MI355X/gfx950. Round 7.
// R6 post-mortem: __launch_bounds__(512,4) capped VGPR at 64 -> massive scratch
// spill (WRITE_SIZE 88.7MB vs ~6MB algorithmic), mega = 570us with all pipes
// idle. R7 keeps the fused 2-dispatch structure but gives the allocator room:
// NBLK=256 blocks x 512 threads, __launch_bounds__(512,2) -> VGPR cap 256,
// exactly 1 block/CU (co-residency for the grid barrier guaranteed).
// Numerics identical to R5/R6.

#define B_       64
#define DMODEL   2048
#define DSSM     4096
#define NH       64
#define HD       64
#define DSTATE   128
#define DPROJ    8512
#define XBCLEN   4352   // DSSM + 2*DSTATE
#define NBLK     256
#define NTHR     512
#define LSTRIDE1 (DMODEL / 4 + 4)   // 516 uints, pad vs bank conflicts
#define LSTRIDE2 (DSSM / 4 + 4)     // 1028 uints

typedef __attribute__((ext_vector_type(4))) int int4v;

__device__ __forceinline__ float absmax4(float4 v) {
  return fmaxf(fmaxf(fabsf(v.x), fabsf(v.y)), fmaxf(fabsf(v.z), fabsf(v.w)));
}

__device__ __forceinline__ unsigned int pack4(float a, float b, float c, float d,
                                              float rs) {
  int c0 = (int)rintf(a * rs), c1 = (int)rintf(b * rs);
  int c2 = (int)rintf(c * rs), c3 = (int)rintf(d * rs);
  return (unsigned)(c0 & 255) | ((unsigned)(c1 & 255) << 8) |
         ((unsigned)(c2 & 255) << 16) | ((unsigned)(c3 & 255) << 24);
}

__device__ __forceinline__ float waveMax(float v) {
  #pragma unroll
  for (int off = 32; off > 0; off >>= 1)
    v = fmaxf(v, __shfl_xor(v, off, 64));
  return v;
}

// block-wide max for 512-thread blocks (8 waves)
__device__ __forceinline__ float blockMax512(float v, float* sm) {
  v = waveMax(v);
  __syncthreads();
  if ((threadIdx.x & 63) == 0) sm[threadIdx.x >> 6] = v;
  __syncthreads();
  float m = sm[0];
  #pragma unroll
  for (int i = 1; i < 8; i++) m = fmaxf(m, sm[i]);
  return m;
}

// device-scope grid barrier; bar[0]=arrive count, bar[1]=generation.
// Safe: NBLK=256 blocks, 1 block/CU (launch_bounds 512,2 + 33KB LDS), all
// co-resident by construction.
__device__ __forceinline__ void gridbar(unsigned* bar) {
  __syncthreads();
  if (threadIdx.x == 0) {
    __threadfence();
    unsigned* cnt = bar;
    unsigned* gen = bar + 1;
    unsigned g = __hip_atomic_load(gen, __ATOMIC_RELAXED, __HIP_MEMORY_SCOPE_AGENT);
    unsigned a = __hip_atomic_fetch_add(cnt, 1u, __ATOMIC_ACQ_REL,
                                        __HIP_MEMORY_SCOPE_AGENT);
    if (a == NBLK - 1) {
      __hip_atomic_store(cnt, 0u, __ATOMIC_RELAXED, __HIP_MEMORY_SCOPE_AGENT);
      __hip_atomic_store(gen, g + 1u, __ATOMIC_RELEASE, __HIP_MEMORY_SCOPE_AGENT);
    } else {
      while (__hip_atomic_load(gen, __ATOMIC_ACQUIRE, __HIP_MEMORY_SCOPE_AGENT) == g)
        __builtin_amdgcn_s_sleep(8);
    }
    __threadfence();
  }
  __syncthreads();
}

// ---------- dispatch 1: quantize hidden (64 x 2048) -> int8, init barrier ----
__global__ __launch_bounds__(256) void quantx(const float* __restrict__ in,
                                              unsigned int* __restrict__ outq,
                                              float* __restrict__ scales,
                                              unsigned* __restrict__ bar) {
  __shared__ float sm[4];
  int r = blockIdx.x;
  const float4* row = (const float4*)(in + (size_t)r * DMODEL);
  float4 v[2];
  float m = 0.f;
  #pragma unroll
  for (int i = 0; i < 2; i++) {
    v[i] = row[threadIdx.x + i * 256];
    m = fmaxf(m, absmax4(v[i]));
  }
  m = waveMax(m);
  __syncthreads();
  if ((threadIdx.x & 63) == 0) sm[threadIdx.x >> 6] = m;
  __syncthreads();
  float mx = fmaxf(fmaxf(sm[0], sm[1]), fmaxf(sm[2], sm[3]));
  float s = mx * (1.0f / 127.0f);
  float rs = (s == 0.f) ? 0.f : 127.0f / mx;
  if (s == 0.f) s = 1.f;
  if (threadIdx.x == 0) scales[r] = s;
  unsigned int* orow = outq + (size_t)r * (DMODEL / 4);
  #pragma unroll
  for (int i = 0; i < 2; i++)
    orow[threadIdx.x + i * 256] = pack4(v[i].x, v[i].y, v[i].z, v[i].w, rs);
  if (r == 0 && threadIdx.x == 0) { bar[0] = 0u; bar[1] = 0u; }
}

// ---------- dispatch 2: fused pipeline ----------
__global__ __launch_bounds__(NTHR, 2) void mega(
    const float* __restrict__ W_in, const char* __restrict__ Aq,
    const float* __restrict__ sA, float* __restrict__ zxb,
    const float* __restrict__ dt_bias, const float* __restrict__ A_log,
    float* __restrict__ zbuf, float* __restrict__ xbcq,
    float* __restrict__ coefs, const float* __restrict__ ssm,
    float* __restrict__ yraw, const float* __restrict__ Dv,
    unsigned int* __restrict__ q3, float* __restrict__ sy,
    const float* __restrict__ W_out, float* __restrict__ out,
    unsigned* __restrict__ bar) {
  __shared__ union {
    struct { unsigned int wq[16 * LSTRIDE1]; float smax[16]; } g1;   // 33,088 B
    struct { unsigned int wq[4 * LSTRIDE2]; float smax[4]; float hmax[4][2]; } g2;
    struct { float dts[NH]; float sm[8]; float sbc; } mid;
    float sm[8];
  } S;

  int t = threadIdx.x, wave = t >> 6, lane = t & 63;
  int bid = blockIdx.x;
  int l16 = lane & 15, quad = lane >> 4;

  // ================= phase 1: fused quant+GEMM1 (zxb = x @ W_in^T) ==========
  for (int tile = bid; tile < DPROJ / 16; tile += NBLK) {
    int n0 = tile * 16;
    // quant 2 weight rows per wave (8 waves x 2 = 16 rows), fp32 read ONCE
    #pragma unroll
    for (int rr = 0; rr < 2; rr++) {
      int row = wave * 2 + rr;
      const float4* rp = (const float4*)(W_in + (size_t)(n0 + row) * DMODEL);
      float4 v[8];
      float m = 0.f;
      #pragma unroll
      for (int c = 0; c < 8; c++) {
        v[c] = rp[lane + c * 64];
        m = fmaxf(m, absmax4(v[c]));
      }
      m = waveMax(m);
      float s = (m == 0.f) ? 1.f : m * (1.0f / 127.0f);
      float rs = (m == 0.f) ? 0.f : 127.0f / m;
      if (lane == 0) S.g1.smax[row] = s;
      unsigned int* wrow = S.g1.wq + row * LSTRIDE1;
      #pragma unroll
      for (int c = 0; c < 8; c++)
        wrow[lane + c * 64] = pack4(v[c].x, v[c].y, v[c].z, v[c].w, rs);
    }
    __syncthreads();
    // MFMA: wave = (m-tile 0..3, n-half 0..1); C/D: col=lane&15, row=quad*4+reg
    int m4 = wave >> 1, nh = wave & 1;
    int4v acc = {0, 0, 0, 0};
    const char* arow = Aq + (size_t)(m4 * 16 + l16) * DMODEL + quad * 16;
    const unsigned int* brow = S.g1.wq + (nh * 8 + l16) * LSTRIDE1 + quad * 4;
    for (int k = 0; k < DMODEL; k += 256) {
      int4v af[4], bf[4];
      #pragma unroll
      for (int u = 0; u < 4; u++)
        af[u] = *(const int4v*)(arow + k + u * 64);
      #pragma unroll
      for (int u = 0; u < 4; u++) {
        int4v z = {0, 0, 0, 0};
        bf[u] = z;
        if (l16 < 8) bf[u] = *(const int4v*)(brow + (k + u * 64) / 4);
      }
      #pragma unroll
      for (int u = 0; u < 4; u++)
        acc = __builtin_amdgcn_mfma_i32_16x16x64_i8(af[u], bf[u], acc, 0, 0, 0);
    }
    if (l16 < 8) {
      float sw = S.g1.smax[nh * 8 + l16];
      #pragma unroll
      for (int r = 0; r < 4; r++) {
        int mr = m4 * 16 + quad * 4 + r;
        zxb[(size_t)mr * DPROJ + n0 + nh * 8 + l16] = (float)acc[r] * sA[mr] * sw;
      }
    }
    __syncthreads();   // wq reused by next tile
  }
  gridbar(bar);

  // ================= phase 2: kmid (split z/xBC/dt, quant xBC, coefs) =======
  if (bid < B_) {
    int b = bid;
    float4 v[5];
    float m = 0.f;
    float4 q8 = {0.f, 0.f, 0.f, 0.f};
    #pragma unroll
    for (int i = 0; i < 5; i++) {
      int idx = t + i * 512;
      if (idx < 2128) {
        float4 a = ((const float4*)(zxb + (size_t)b * DPROJ))[idx];
        v[i] = a;
        if (idx >= 1024 && idx < 2112) m = fmaxf(m, absmax4(a));
        if (idx >= 2112) {                 // dt segment: i==4, t in [64,80)
          S.mid.dts[(idx - 2112) * 4 + 0] = a.x;
          S.mid.dts[(idx - 2112) * 4 + 1] = a.y;
          S.mid.dts[(idx - 2112) * 4 + 2] = a.z;
          S.mid.dts[(idx - 2112) * 4 + 3] = a.w;
        }
      }
    }
    float mx = blockMax512(m, S.mid.sm);   // barrier also publishes dts[]
    float s = mx * (1.0f / 127.0f);
    float rs = (s == 0.f) ? 0.f : 127.0f / mx;
    if (s == 0.f) s = 1.f;
    #pragma unroll
    for (int i = 0; i < 5; i++) {
      int idx = t + i * 512;
      if (idx < 1024) {
        ((float4*)(zbuf + (size_t)b * DSSM))[idx] = v[i];
      } else if (idx < 2112) {
        float4 q;
        q.x = rintf(v[i].x * rs) * s;
        q.y = rintf(v[i].y * rs) * s;
        q.z = rintf(v[i].z * rs) * s;
        q.w = rintf(v[i].w * rs) * s;
        if (i == 4 && t < 64) q8 = q;      // B/C f4s live at idx 2048..2111
        ((float4*)(xbcq + (size_t)b * XBCLEN))[idx - 1024] = q;
      }
    }
    // B.C from quantized values (wave 0: lanes 0..31 = B, 32..63 = C)
    float4 oth;
    oth.x = __shfl(q8.x, lane ^ 32, 64);
    oth.y = __shfl(q8.y, lane ^ 32, 64);
    oth.z = __shfl(q8.z, lane ^ 32, 64);
    oth.w = __shfl(q8.w, lane ^ 32, 64);
    float p = 0.f;
    if (t < 32) p = q8.x * oth.x + q8.y * oth.y + q8.z * oth.z + q8.w * oth.w;
    #pragma unroll
    for (int off = 1; off < 32; off <<= 1) p += __shfl_xor(p, off, 64);
    if (t == 0) S.mid.sbc = p;
    __syncthreads();
    if (t < NH) {
      float dtv = S.mid.dts[t] + dt_bias[t];
      if (dtv < -2.f) dtv = 0.f;
      else if (dtv <= 2.f)
        dtv = 0.6931471805599453f + 0.5f * dtv + dtv * dtv * (1.f / 8.f)
              + dtv * dtv * dtv * (1.f / 48.f);
      float A = -expf(A_log[t]);
      float dA = fmaxf(dtv * A, -10000.f);
      float e = 1.f + dA + dA * dA * (1.f / 2.f) + dA * dA * dA * (1.f / 6.f)
                + dA * dA * dA * dA * (1.f / 24.f)
                + dA * dA * dA * dA * dA * (1.f / 120.f);
      e = fminf(fmaxf(e, 0.f), 1.f);
      coefs[((size_t)b * NH + t) * 2 + 0] = e;
      coefs[((size_t)b * NH + t) * 2 + 1] = dtv * S.mid.sbc;
    }
  }
  gridbar(bar);

  // ================= phase 3: SSM contraction (16 jobs/block, exact) ========
  {
    int half = t >> 8, th = t & 255;
    #pragma unroll 2
    for (int jj = 0; jj < 8; jj++) {
      int job = bid * 16 + half * 8 + jj;     // 256*16 = 4096 = B_*NH
      int b = job >> 6, h = job & 63;
      const float* xrow = xbcq + (size_t)b * XBCLEN;
      float4 c4 = *(const float4*)(xrow + DSSM + DSTATE + (th & 31) * 4);
      float2 cf = *(const float2*)(coefs + ((size_t)b * NH + h) * 2);
      const float4* st = (const float4*)(ssm + ((size_t)b * NH + h) * (HD * DSTATE));
      #pragma unroll
      for (int j = 0; j < 8; j++) {
        float4 s4 = st[j * 256 + th];
        float acc = s4.x * c4.x + s4.y * c4.y + s4.z * c4.z + s4.w * c4.w;
        #pragma unroll
        for (int off = 1; off < 32; off <<= 1) acc += __shfl_xor(acc, off, 64);
        if ((th & 31) == 0) {
          int r = j * 8 + (th >> 5);
          int d = h * HD + r;
          yraw[(size_t)b * DSSM + d] = cf.x * acc + cf.y * xrow[d];
        }
      }
    }
  }
  gridbar(bar);

  // ================= phase 4: epilogue fq -> +D*x -> *relu(z) -> fq =========
  if (bid < B_) {
    int b = bid;
    const float* yrow = yraw + (size_t)b * DSSM;
    float4 yv[2];
    float m = 0.f;
    #pragma unroll
    for (int i = 0; i < 2; i++) {
      yv[i] = ((const float4*)yrow)[t + i * 512];
      m = fmaxf(m, absmax4(yv[i]));
    }
    float mx1 = blockMax512(m, S.sm);
    float s1 = mx1 * (1.0f / 127.0f);
    float rs1 = (s1 == 0.f) ? 0.f : 127.0f / mx1;
    if (s1 == 0.f) s1 = 1.f;
    float4 y3[2];
    float m2 = 0.f;
    #pragma unroll
    for (int i = 0; i < 2; i++) {
      int idx = t + i * 512;
      float4 x4 = ((const float4*)(xbcq + (size_t)b * XBCLEN))[idx];
      float4 z4 = ((const float4*)(zbuf + (size_t)b * DSSM))[idx];
      float4 d4 = ((const float4*)Dv)[idx];
      float4 r;
      r.x = (rintf(yv[i].x * rs1) * s1 + d4.x * x4.x) * fmaxf(z4.x, 0.f);
      r.y = (rintf(yv[i].y * rs1) * s1 + d4.y * x4.y) * fmaxf(z4.y, 0.f);
      r.z = (rintf(yv[i].z * rs1) * s1 + d4.z * x4.z) * fmaxf(z4.z, 0.f);
      r.w = (rintf(yv[i].w * rs1) * s1 + d4.w * x4.w) * fmaxf(z4.w, 0.f);
      y3[i] = r;
      m2 = fmaxf(m2, absmax4(r));
    }
    float mx3 = blockMax512(m2, S.sm);
    float s3 = mx3 * (1.0f / 127.0f);
    float rs3 = (s3 == 0.f) ? 0.f : 127.0f / mx3;
    if (s3 == 0.f) s3 = 1.f;
    if (t == 0) sy[b] = s3;
    unsigned int* orow = q3 + (size_t)b * (DSSM / 4);
    #pragma unroll
    for (int i = 0; i < 2; i++)
      orow[t + i * 512] = pack4(y3[i].x, y3[i].y, y3[i].z, y3[i].w, rs3);
  }
  gridbar(bar);

  // ================= phase 5: fused quant+GEMM2 -> out (2 tiles/block) ======
  for (int tile = bid; tile < DMODEL / 4; tile += NBLK) {
    int n0 = tile * 4;
    // quant 4 weight rows; 2 waves per row, each does half of K=4096
    {
      int row = wave >> 1, kh = wave & 1;
      const float4* rp = (const float4*)(W_out + (size_t)(n0 + row) * DSSM);
      float4 v[8];
      float m = 0.f;
      #pragma unroll
      for (int c = 0; c < 8; c++) {
        v[c] = rp[lane + (kh * 8 + c) * 64];
        m = fmaxf(m, absmax4(v[c]));
      }
      m = waveMax(m);
      if (lane == 0) S.g2.hmax[row][kh] = m;
      __syncthreads();
      float mm = fmaxf(S.g2.hmax[row][0], S.g2.hmax[row][1]);
      float s = (mm == 0.f) ? 1.f : mm * (1.0f / 127.0f);
      float rs = (mm == 0.f) ? 0.f : 127.0f / mm;
      if (lane == 0 && kh == 0) S.g2.smax[row] = s;
      unsigned int* wrow = S.g2.wq + row * LSTRIDE2;
      #pragma unroll
      for (int c = 0; c < 8; c++)
        wrow[lane + (kh * 8 + c) * 64] = pack4(v[c].x, v[c].y, v[c].z, v[c].w, rs);
    }
    __syncthreads();
    if (wave < 4) {
      int m4 = wave;
      int4v acc = {0, 0, 0, 0};
      const char* arow = (const char*)q3 + (size_t)(m4 * 16 + l16) * DSSM + quad * 16;
      const unsigned int* brow = S.g2.wq + l16 * LSTRIDE2 + quad * 4;
      for (int k = 0; k < DSSM; k += 256) {
        int4v af[4], bf[4];
        #pragma unroll
        for (int u = 0; u < 4; u++)
          af[u] = *(const int4v*)(arow + k + u * 64);
        #pragma unroll
        for (int u = 0; u < 4; u++) {
          int4v z = {0, 0, 0, 0};
          bf[u] = z;
          if (l16 < 4) bf[u] = *(const int4v*)(brow + (k + u * 64) / 4);
        }
        #pragma unroll
        for (int u = 0; u < 4; u++)
          acc = __builtin_amdgcn_mfma_i32_16x16x64_i8(af[u], bf[u], acc, 0, 0, 0);
      }
      if (l16 < 4) {
        float sw = S.g2.smax[l16];
        #pragma unroll
        for (int r = 0; r < 4; r++) {
          int mr = m4 * 16 + quad * 4 + r;
          out[(size_t)mr * DMODEL + n0 + l16] = (float)acc[r] * sy[mr] * sw;
        }
      }
    }
    __syncthreads();   // wq reused by next tile
  }
}

extern "C" void kernel_launch(void* const* d_in, const int* in_sizes, int n_in,
                              void* d_out, int out_size, void* d_ws, size_t ws_size,
                              hipStream_t stream) {
  const float* hidden  = (const float*)d_in[0];
  const float* ssm     = (const float*)d_in[1];
  const float* W_in    = (const float*)d_in[2];
  const float* dt_bias = (const float*)d_in[3];
  const float* A_log   = (const float*)d_in[4];
  const float* Dv      = (const float*)d_in[5];
  const float* W_out   = (const float*)d_in[6];
  float* out = (float*)d_out;

  char* p = (char*)d_ws;
  auto alloc = [&](size_t bytes) {
    char* r = p;
    p += (bytes + 255) & ~(size_t)255;
    return r;
  };
  unsigned int* xq = (unsigned int*)alloc((size_t)B_ * DMODEL);
  unsigned int* q3 = (unsigned int*)alloc((size_t)B_ * DSSM);
  float* sx    = (float*)alloc(B_ * 4);
  float* sy    = (float*)alloc(B_ * 4);
  float* zxb   = (float*)alloc((size_t)B_ * DPROJ * 4);
  float* zbuf  = (float*)alloc((size_t)B_ * DSSM * 4);
  float* xbcq  = (float*)alloc((size_t)B_ * XBCLEN * 4);
  float* coefs = (float*)alloc((size_t)B_ * NH * 2 * 4);
  float* yraw  = (float*)alloc((size_t)B_ * DSSM * 4);
  unsigned* bar = (unsigned*)alloc(256);

  quantx<<<B_, 256, 0, stream>>>(hidden, xq, sx, bar);
  mega<<<NBLK, NTHR, 0, stream>>>(W_in, (const char*)xq, sx, zxb, dt_bias, A_log,
                                  zbuf, xbcq, coefs, ssm, yraw, Dv, q3, sy,
                                  W_out, out, bar);
}

// Round 3
// 311.311 us; speedup vs baseline: 2.3986x; 1.6178x over previous
//
#include <hip/hip_runtime.h>

// Mamba2 quantized decode step, MI355X/gfx950. Round 8.
// R6/R7 post-mortem: persistent-kernel fusion pins occupancy at 8 waves/CU ->
// latency-stalled (mega 330us, VALUBusy 3%). Revert to the R5 6-dispatch
// structure (306us baseline) and raise memory-level parallelism instead:
//  - fgemm1: ROWS 16->8, grid 1064 (2x waves/CU, 16.5KB LDS -> 4 blocks/CU)
//  - fgemm2: 512-thr kernel, 2 waves/row quant (16 waves/CU, half the VGPRs)
//  - ky: explicit 8-load register prefetch + 8 interleaved reduce chains
// Numerics identical to R5 (absmax 0.046875).

#define B_       64
#define DMODEL   2048
#define DSSM     4096
#define NH       64
#define HD       64
#define DSTATE   128
#define DPROJ    8512
#define XBCLEN   4352   // DSSM + 2*DSTATE
#define LSTRIDE2 (DSSM / 4 + 4)     // 1028 uints, padded vs bank conflicts

typedef __attribute__((ext_vector_type(4))) int int4v;

__device__ __forceinline__ float blockMax256(float v, float* sm) {
  #pragma unroll
  for (int off = 32; off > 0; off >>= 1)
    v = fmaxf(v, __shfl_xor(v, off, 64));
  __syncthreads();
  if ((threadIdx.x & 63) == 0) sm[threadIdx.x >> 6] = v;
  __syncthreads();
  return fmaxf(fmaxf(sm[0], sm[1]), fmaxf(sm[2], sm[3]));
}

__device__ __forceinline__ float absmax4(float4 v) {
  return fmaxf(fmaxf(fabsf(v.x), fabsf(v.y)), fmaxf(fabsf(v.z), fabsf(v.w)));
}

__device__ __forceinline__ float waveMax(float v) {
  #pragma unroll
  for (int off = 32; off > 0; off >>= 1)
    v = fmaxf(v, __shfl_xor(v, off, 64));
  return v;
}

__device__ __forceinline__ unsigned int pack4(float a, float b, float c, float d,
                                              float rs) {
  int c0 = (int)rintf(a * rs), c1 = (int)rintf(b * rs);
  int c2 = (int)rintf(c * rs), c3 = (int)rintf(d * rs);
  return (unsigned)(c0 & 255) | ((unsigned)(c1 & 255) << 8) |
         ((unsigned)(c2 & 255) << 16) | ((unsigned)(c3 & 255) << 24);
}

// ---------- quantize hidden (64 rows x 2048) -> int8 + scale ----------
__global__ __launch_bounds__(256) void quantx(const float* __restrict__ in,
                                              unsigned int* __restrict__ outq,
                                              float* __restrict__ scales) {
  __shared__ float sm[4];
  int r = blockIdx.x;
  const float4* row = (const float4*)(in + (size_t)r * DMODEL);
  float4 v[2];
  float m = 0.f;
  #pragma unroll
  for (int i = 0; i < 2; i++) {
    v[i] = row[threadIdx.x + i * 256];
    m = fmaxf(m, absmax4(v[i]));
  }
  float mx = blockMax256(m, sm);
  float s = mx * (1.0f / 127.0f);
  float rs = (s == 0.f) ? 0.f : 127.0f / mx;
  if (s == 0.f) s = 1.f;
  if (threadIdx.x == 0) scales[r] = s;
  unsigned int* orow = outq + (size_t)r * (DMODEL / 4);
  #pragma unroll
  for (int i = 0; i < 2; i++)
    orow[threadIdx.x + i * 256] = pack4(v[i].x, v[i].y, v[i].z, v[i].w, rs);
}

// ---------- fused quant+GEMM (W_in path): block owns ROWS weight rows ----------
template<int K, int ROWS>
__global__ __launch_bounds__(256) void fgemm(const float* __restrict__ W,
                                             const char* __restrict__ Aq,
                                             const float* __restrict__ sA,
                                             float* __restrict__ Cout, int N) {
  constexpr int NF4 = K / 256;        // float4 per lane per row
  constexpr int RPW = ROWS / 4;       // rows per wave (4 waves)
  constexpr int LSTRIDE = K / 4 + 4;  // uints, padded vs bank conflicts
  __shared__ unsigned int wq[ROWS * LSTRIDE];
  __shared__ float smax[ROWS];
  int t = threadIdx.x, wave = t >> 6, lane = t & 63;
  int n0 = blockIdx.x * ROWS;
  #pragma unroll
  for (int rr = 0; rr < RPW; rr++) {
    int row = wave * RPW + rr;
    const float4* rp = (const float4*)(W + (size_t)(n0 + row) * K);
    float4 v[NF4];
    float m = 0.f;
    #pragma unroll
    for (int c = 0; c < NF4; c++) {
      v[c] = rp[lane + c * 64];
      m = fmaxf(m, absmax4(v[c]));
    }
    m = waveMax(m);
    float s = (m == 0.f) ? 1.f : m * (1.0f / 127.0f);
    float rs = (m == 0.f) ? 0.f : 127.0f / m;
    if (lane == 0) smax[row] = s;
    unsigned int* wrow = wq + row * LSTRIDE;
    #pragma unroll
    for (int c = 0; c < NF4; c++)
      wrow[lane + c * 64] = pack4(v[c].x, v[c].y, v[c].z, v[c].w, rs);
  }
  __syncthreads();
  int l16 = lane & 15, quad = lane >> 4;
  int4v acc = {0, 0, 0, 0};
  const char* arow = Aq + (size_t)(wave * 16 + l16) * K + quad * 16;
  const unsigned int* brow = wq + l16 * LSTRIDE + quad * 4;
  for (int k = 0; k < K; k += 256) {          // 4 MFMAs per iter, batched loads
    int4v af[4], bf[4];
    #pragma unroll
    for (int u = 0; u < 4; u++)
      af[u] = *(const int4v*)(arow + k + u * 64);
    #pragma unroll
    for (int u = 0; u < 4; u++) {
      int4v z = {0, 0, 0, 0};
      bf[u] = z;
      if (l16 < ROWS) bf[u] = *(const int4v*)(brow + (k + u * 64) / 4);
    }
    #pragma unroll
    for (int u = 0; u < 4; u++)
      acc = __builtin_amdgcn_mfma_i32_16x16x64_i8(af[u], bf[u], acc, 0, 0, 0);
  }
  if (l16 < ROWS) {
    float sw = smax[l16];
    #pragma unroll
    for (int r = 0; r < 4; r++) {
      int m = wave * 16 + quad * 4 + r;   // C/D: col=lane&15, row=quad*4+reg (m89)
      Cout[(size_t)m * N + n0 + l16] = (float)acc[r] * sA[m] * sw;
    }
  }
}

// ---------- fused quant+GEMM2 (W_out path): 512 thr, 2 waves per weight row ----
__global__ __launch_bounds__(512) void fgemm2k(const float* __restrict__ W,
                                               const char* __restrict__ Aq,
                                               const float* __restrict__ sA,
                                               float* __restrict__ Cout) {
  __shared__ unsigned int wq[4 * LSTRIDE2];   // 16.4 KB
  __shared__ float smax[4];
  __shared__ float hmax[4][2];
  int t = threadIdx.x, wave = t >> 6, lane = t & 63;
  int l16 = lane & 15, quad = lane >> 4;
  int n0 = blockIdx.x * 4;
  // quant 4 weight rows; 2 waves per row, each does half of K=4096
  {
    int row = wave >> 1, kh = wave & 1;
    const float4* rp = (const float4*)(W + (size_t)(n0 + row) * DSSM);
    float4 v[8];
    float m = 0.f;
    #pragma unroll
    for (int c = 0; c < 8; c++) {
      v[c] = rp[lane + (kh * 8 + c) * 64];
      m = fmaxf(m, absmax4(v[c]));
    }
    m = waveMax(m);
    if (lane == 0) hmax[row][kh] = m;
    __syncthreads();
    float mm = fmaxf(hmax[row][0], hmax[row][1]);
    float s = (mm == 0.f) ? 1.f : mm * (1.0f / 127.0f);
    float rs = (mm == 0.f) ? 0.f : 127.0f / mm;
    if (lane == 0 && kh == 0) smax[row] = s;
    unsigned int* wrow = wq + row * LSTRIDE2;
    #pragma unroll
    for (int c = 0; c < 8; c++)
      wrow[lane + (kh * 8 + c) * 64] = pack4(v[c].x, v[c].y, v[c].z, v[c].w, rs);
  }
  __syncthreads();
  if (wave < 4) {
    int m4 = wave;
    int4v acc = {0, 0, 0, 0};
    const char* arow = Aq + (size_t)(m4 * 16 + l16) * DSSM + quad * 16;
    const unsigned int* brow = wq + l16 * LSTRIDE2 + quad * 4;
    for (int k = 0; k < DSSM; k += 256) {
      int4v af[4], bf[4];
      #pragma unroll
      for (int u = 0; u < 4; u++)
        af[u] = *(const int4v*)(arow + k + u * 64);
      #pragma unroll
      for (int u = 0; u < 4; u++) {
        int4v z = {0, 0, 0, 0};
        bf[u] = z;
        if (l16 < 4) bf[u] = *(const int4v*)(brow + (k + u * 64) / 4);
      }
      #pragma unroll
      for (int u = 0; u < 4; u++)
        acc = __builtin_amdgcn_mfma_i32_16x16x64_i8(af[u], bf[u], acc, 0, 0, 0);
    }
    if (l16 < 4) {
      float sw = smax[l16];
      #pragma unroll
      for (int r = 0; r < 4; r++) {
        int mr = m4 * 16 + quad * 4 + r;
        Cout[(size_t)mr * DMODEL + n0 + l16] = (float)acc[r] * sA[mr] * sw;
      }
    }
  }
}

// ---------- kmid: split z/xBC/dt from zxb, quant xBC, coefs ----------
__global__ __launch_bounds__(256) void kmid(
    const float* __restrict__ P1, const float* __restrict__ dt_bias,
    const float* __restrict__ A_log,
    float* __restrict__ zbuf, float* __restrict__ xbcq, float* __restrict__ coefs) {
  __shared__ float sm[4];
  __shared__ float dts[NH];
  __shared__ float sbc;
  int b = blockIdx.x, t = threadIdx.x;
  float4 v[9];
  float m = 0.f;
  #pragma unroll
  for (int i = 0; i < 9; i++) {
    int idx = t + i * 256;                   // float4 index within 2128-wide row
    if (idx < 2128) {
      float4 a = ((const float4*)P1)[(size_t)b * 2128 + idx];
      v[i] = a;
      if (idx >= 1024 && idx < 2112) m = fmaxf(m, absmax4(a));
      if (idx >= 2112) {                      // dt segment: t in [64,80)
        dts[(t - 64) * 4 + 0] = a.x;
        dts[(t - 64) * 4 + 1] = a.y;
        dts[(t - 64) * 4 + 2] = a.z;
        dts[(t - 64) * 4 + 3] = a.w;
      }
    }
  }
  float mx = blockMax256(m, sm);             // barrier also publishes dts[]
  float s = mx * (1.0f / 127.0f);
  float rs = (s == 0.f) ? 0.f : 127.0f / mx;
  if (s == 0.f) s = 1.f;
  float4 q8 = {0.f, 0.f, 0.f, 0.f};          // quantized i==8 f4 (B/C), t<64
  #pragma unroll
  for (int i = 0; i < 9; i++) {
    int idx = t + i * 256;
    if (idx < 1024) {
      *((float4*)(zbuf + (size_t)b * DSSM) + idx) = v[i];
    } else if (idx < 2112) {
      float4 q;
      q.x = rintf(v[i].x * rs) * s;
      q.y = rintf(v[i].y * rs) * s;
      q.z = rintf(v[i].z * rs) * s;
      q.w = rintf(v[i].w * rs) * s;
      if (i == 8) q8 = q;
      *((float4*)(xbcq + (size_t)b * XBCLEN) + (idx - 1024)) = q;
    }
  }
  // B.C from quantized values: lanes 0..31 hold B f4s, 32..63 hold C f4s (wave 0)
  float4 oth;
  oth.x = __shfl(q8.x, (t & 63) ^ 32, 64);
  oth.y = __shfl(q8.y, (t & 63) ^ 32, 64);
  oth.z = __shfl(q8.z, (t & 63) ^ 32, 64);
  oth.w = __shfl(q8.w, (t & 63) ^ 32, 64);
  float p = 0.f;
  if (t < 32) p = q8.x * oth.x + q8.y * oth.y + q8.z * oth.z + q8.w * oth.w;
  #pragma unroll
  for (int off = 1; off < 32; off <<= 1) p += __shfl_xor(p, off, 64);
  if (t == 0) sbc = p;
  __syncthreads();
  if (t < NH) {
    float dtv = dts[t] + dt_bias[t];
    if (dtv < -2.f) dtv = 0.f;
    else if (dtv <= 2.f)
      dtv = 0.6931471805599453f + 0.5f * dtv + dtv * dtv * (1.f / 8.f)
            + dtv * dtv * dtv * (1.f / 48.f);
    float A = -expf(A_log[t]);
    float dA = fmaxf(dtv * A, -10000.f);
    float e = 1.f + dA + dA * dA * (1.f / 2.f) + dA * dA * dA * (1.f / 6.f)
              + dA * dA * dA * dA * (1.f / 24.f)
              + dA * dA * dA * dA * dA * (1.f / 120.f);
    e = fminf(fmaxf(e, 0.f), 1.f);
    coefs[((size_t)b * NH + t) * 2 + 0] = e;           // sc
    coefs[((size_t)b * NH + t) * 2 + 1] = dtv * sbc;   // dt*(B.C)
  }
}

// ---------- SSM contraction: block per (b,h); 8-deep load prefetch ----------
__global__ __launch_bounds__(256) void ky(const float* __restrict__ state,
                                          const float* __restrict__ xbcq,
                                          const float* __restrict__ coefs,
                                          float* __restrict__ yraw) {
  int h = blockIdx.x, b = blockIdx.y, t = threadIdx.x;
  const float* xrow = xbcq + (size_t)b * XBCLEN;
  const float* Cv = xrow + DSSM + DSTATE;
  float4 c4 = *(const float4*)(Cv + (t & 31) * 4);
  float2 cf = *(const float2*)(coefs + ((size_t)b * NH + h) * 2);  // {sc, coef}
  const float4* st = (const float4*)(state + ((size_t)b * NH + h) * (HD * DSTATE));
  float4 s4[8];                              // all 8 loads issued before any use
  #pragma unroll
  for (int j = 0; j < 8; j++) s4[j] = st[j * 256 + t];
  float acc[8];
  #pragma unroll
  for (int j = 0; j < 8; j++)
    acc[j] = s4[j].x * c4.x + s4[j].y * c4.y + s4[j].z * c4.z + s4[j].w * c4.w;
  #pragma unroll
  for (int off = 1; off < 32; off <<= 1) {   // 8 interleaved reduce chains (ILP)
    #pragma unroll
    for (int j = 0; j < 8; j++) acc[j] += __shfl_xor(acc[j], off, 64);
  }
  if ((t & 31) == 0) {
    #pragma unroll
    for (int j = 0; j < 8; j++) {
      int r = j * 8 + (t >> 5);
      int d = h * HD + r;
      yraw[(size_t)b * DSSM + d] = cf.x * acc[j] + cf.y * xrow[d];
    }
  }
}

// ---------- epilogue: fq(y) -> +D*x -> *relu(z) -> fq -> int8 levels ----------
__global__ __launch_bounds__(256) void kepi(const float* __restrict__ yraw,
                                            const float* __restrict__ zbuf,
                                            const float* __restrict__ xbcq,
                                            const float* __restrict__ Dv,
                                            unsigned int* __restrict__ q3,
                                            float* __restrict__ sy) {
  __shared__ float sm[4];
  int b = blockIdx.x, t = threadIdx.x;
  const float* yrow = yraw + (size_t)b * DSSM;
  float4 yv[4];
  float m = 0.f;
  #pragma unroll
  for (int i = 0; i < 4; i++) {
    yv[i] = *(const float4*)(yrow + t * 4 + i * 1024);
    m = fmaxf(m, absmax4(yv[i]));
  }
  float mx1 = blockMax256(m, sm);
  float s1 = mx1 * (1.0f / 127.0f);
  float rs1 = (s1 == 0.f) ? 0.f : 127.0f / mx1;
  if (s1 == 0.f) s1 = 1.f;
  float4 y3[4];
  float m2 = 0.f;
  #pragma unroll
  for (int i = 0; i < 4; i++) {
    int idx = t * 4 + i * 1024;
    float4 x4 = *(const float4*)(xbcq + (size_t)b * XBCLEN + idx);
    float4 z4 = *(const float4*)(zbuf + (size_t)b * DSSM + idx);
    float4 d4 = *(const float4*)(Dv + idx);
    float4 r;
    r.x = (rintf(yv[i].x * rs1) * s1 + d4.x * x4.x) * fmaxf(z4.x, 0.f);
    r.y = (rintf(yv[i].y * rs1) * s1 + d4.y * x4.y) * fmaxf(z4.y, 0.f);
    r.z = (rintf(yv[i].z * rs1) * s1 + d4.z * x4.z) * fmaxf(z4.z, 0.f);
    r.w = (rintf(yv[i].w * rs1) * s1 + d4.w * x4.w) * fmaxf(z4.w, 0.f);
    y3[i] = r;
    m2 = fmaxf(m2, absmax4(r));
  }
  float mx3 = blockMax256(m2, sm);
  float s3 = mx3 * (1.0f / 127.0f);
  float rs3 = (s3 == 0.f) ? 0.f : 127.0f / mx3;
  if (s3 == 0.f) s3 = 1.f;
  if (t == 0) sy[b] = s3;
  unsigned int* orow = q3 + (size_t)b * (DSSM / 4);
  #pragma unroll
  for (int i = 0; i < 4; i++)
    orow[t + i * 256] = pack4(y3[i].x, y3[i].y, y3[i].z, y3[i].w, rs3);
}

extern "C" void kernel_launch(void* const* d_in, const int* in_sizes, int n_in,
                              void* d_out, int out_size, void* d_ws, size_t ws_size,
                              hipStream_t stream) {
  const float* hidden  = (const float*)d_in[0];
  const float* ssm     = (const float*)d_in[1];
  const float* W_in    = (const float*)d_in[2];
  const float* dt_bias = (const float*)d_in[3];
  const float* A_log   = (const float*)d_in[4];
  const float* Dv      = (const float*)d_in[5];
  const float* W_out   = (const float*)d_in[6];
  float* out = (float*)d_out;

  char* p = (char*)d_ws;
  auto alloc = [&](size_t bytes) {
    char* r = p;
    p += (bytes + 255) & ~(size_t)255;
    return r;
  };
  unsigned int* xq = (unsigned int*)alloc((size_t)B_ * DMODEL);
  unsigned int* q3 = (unsigned int*)alloc((size_t)B_ * DSSM);
  float* sx    = (float*)alloc(B_ * 4);
  float* sy    = (float*)alloc(B_ * 4);
  float* zxb   = (float*)alloc((size_t)B_ * DPROJ * 4);    // 2.2 MB
  float* zbuf  = (float*)alloc((size_t)B_ * DSSM * 4);
  float* xbcq  = (float*)alloc((size_t)B_ * XBCLEN * 4);
  float* coefs = (float*)alloc((size_t)B_ * NH * 2 * 4);
  float* yraw  = (float*)alloc((size_t)B_ * DSSM * 4);

  quantx<<<B_, 256, 0, stream>>>(hidden, xq, sx);
  fgemm<DMODEL, 8><<<DPROJ / 8, 256, 0, stream>>>(W_in, (const char*)xq, sx,
                                                  zxb, DPROJ);
  kmid<<<B_, 256, 0, stream>>>(zxb, dt_bias, A_log, zbuf, xbcq, coefs);
  ky<<<dim3(NH, B_), 256, 0, stream>>>(ssm, xbcq, coefs, yraw);
  kepi<<<B_, 256, 0, stream>>>(yraw, zbuf, xbcq, Dv, q3, sy);
  fgemm2k<<<DMODEL / 4, 512, 0, stream>>>(W_out, (const char*)q3, sy, out);
}

// Round 5
// 284.929 us; speedup vs baseline: 2.6207x; 1.0926x over previous
//
#include <hip/hip_runtime.h>

// Mamba2 quantized decode step, MI355X/gfx950. Round 10 (= R9 + compile fix).
// R9 change set: revert to R5 GEMM configs, REMOVE kmid by folding its
// (deterministic, per-row) quant work into ky and kepi:
//  - kyf: recompute xBC absmax from zxb (L2-hot scan, 2 heads/block),
//         quantize C/B/x on the fly, compute dt/e/sbc coefs in-block.
//  - kepif: recompute absmax, quantize x from zxb; read z directly from zxb.
// Saves 1 graph node + gap and the zbuf/xbcq 4.4MB round-trip. Nontemporal
// loads on read-once streams via clang ext-vector type (HIP float4 is not
// accepted by __builtin_nontemporal_load).
// All quant math bit-identical to R5 (absmax 0.046875).

#define B_       64
#define DMODEL   2048
#define DSSM     4096
#define NH       64
#define HD       64
#define DSTATE   128
#define DPROJ    8512
#define XBCLEN   4352   // DSSM + 2*DSTATE

typedef __attribute__((ext_vector_type(4))) int int4v;
typedef __attribute__((ext_vector_type(4))) float f4v;

__device__ __forceinline__ float blockMax256(float v, float* sm) {
  #pragma unroll
  for (int off = 32; off > 0; off >>= 1)
    v = fmaxf(v, __shfl_xor(v, off, 64));
  __syncthreads();
  if ((threadIdx.x & 63) == 0) sm[threadIdx.x >> 6] = v;
  __syncthreads();
  return fmaxf(fmaxf(sm[0], sm[1]), fmaxf(sm[2], sm[3]));
}

__device__ __forceinline__ float absmax4(float4 v) {
  return fmaxf(fmaxf(fabsf(v.x), fabsf(v.y)), fmaxf(fabsf(v.z), fabsf(v.w)));
}

__device__ __forceinline__ float absmax4v(f4v v) {
  return fmaxf(fmaxf(fabsf(v.x), fabsf(v.y)), fmaxf(fabsf(v.z), fabsf(v.w)));
}

__device__ __forceinline__ float waveMax(float v) {
  #pragma unroll
  for (int off = 32; off > 0; off >>= 1)
    v = fmaxf(v, __shfl_xor(v, off, 64));
  return v;
}

__device__ __forceinline__ unsigned int pack4(float a, float b, float c, float d,
                                              float rs) {
  int c0 = (int)rintf(a * rs), c1 = (int)rintf(b * rs);
  int c2 = (int)rintf(c * rs), c3 = (int)rintf(d * rs);
  return (unsigned)(c0 & 255) | ((unsigned)(c1 & 255) << 8) |
         ((unsigned)(c2 & 255) << 16) | ((unsigned)(c3 & 255) << 24);
}

// ---------- quantize hidden (64 rows x 2048) -> int8 + scale ----------
__global__ __launch_bounds__(256) void quantx(const float* __restrict__ in,
                                              unsigned int* __restrict__ outq,
                                              float* __restrict__ scales) {
  __shared__ float sm[4];
  int r = blockIdx.x;
  const float4* row = (const float4*)(in + (size_t)r * DMODEL);
  float4 v[2];
  float m = 0.f;
  #pragma unroll
  for (int i = 0; i < 2; i++) {
    v[i] = row[threadIdx.x + i * 256];
    m = fmaxf(m, absmax4(v[i]));
  }
  float mx = blockMax256(m, sm);
  float s = mx * (1.0f / 127.0f);
  float rs = (s == 0.f) ? 0.f : 127.0f / mx;
  if (s == 0.f) s = 1.f;
  if (threadIdx.x == 0) scales[r] = s;
  unsigned int* orow = outq + (size_t)r * (DMODEL / 4);
  #pragma unroll
  for (int i = 0; i < 2; i++)
    orow[threadIdx.x + i * 256] = pack4(v[i].x, v[i].y, v[i].z, v[i].w, rs);
}

// ---------- fused quant+GEMM (R5 config) ----------
template<int K, int ROWS>
__global__ __launch_bounds__(256) void fgemm(const float* __restrict__ W,
                                             const char* __restrict__ Aq,
                                             const float* __restrict__ sA,
                                             float* __restrict__ Cout, int N) {
  constexpr int NF4 = K / 256;        // float4 per lane per row
  constexpr int RPW = ROWS / 4;       // rows per wave (4 waves)
  constexpr int LSTRIDE = K / 4 + 4;  // uints, padded vs bank conflicts
  __shared__ unsigned int wq[ROWS * LSTRIDE];
  __shared__ float smax[ROWS];
  int t = threadIdx.x, wave = t >> 6, lane = t & 63;
  int n0 = blockIdx.x * ROWS;
  #pragma unroll
  for (int rr = 0; rr < RPW; rr++) {
    int row = wave * RPW + rr;
    const f4v* rp = (const f4v*)(W + (size_t)(n0 + row) * K);
    f4v v[NF4];
    float m = 0.f;
    #pragma unroll
    for (int c = 0; c < NF4; c++) {
      v[c] = __builtin_nontemporal_load(&rp[lane + c * 64]);
      m = fmaxf(m, absmax4v(v[c]));
    }
    m = waveMax(m);
    float s = (m == 0.f) ? 1.f : m * (1.0f / 127.0f);
    float rs = (m == 0.f) ? 0.f : 127.0f / m;
    if (lane == 0) smax[row] = s;
    unsigned int* wrow = wq + row * LSTRIDE;
    #pragma unroll
    for (int c = 0; c < NF4; c++)
      wrow[lane + c * 64] = pack4(v[c].x, v[c].y, v[c].z, v[c].w, rs);
  }
  __syncthreads();
  int l16 = lane & 15, quad = lane >> 4;
  int4v acc = {0, 0, 0, 0};
  const char* arow = Aq + (size_t)(wave * 16 + l16) * K + quad * 16;
  const unsigned int* brow = wq + l16 * LSTRIDE + quad * 4;
  for (int k = 0; k < K; k += 256) {          // 4 MFMAs per iter, batched loads
    int4v af[4], bf[4];
    #pragma unroll
    for (int u = 0; u < 4; u++)
      af[u] = *(const int4v*)(arow + k + u * 64);
    #pragma unroll
    for (int u = 0; u < 4; u++) {
      int4v z = {0, 0, 0, 0};
      bf[u] = z;
      if (l16 < ROWS) bf[u] = *(const int4v*)(brow + (k + u * 64) / 4);
    }
    #pragma unroll
    for (int u = 0; u < 4; u++)
      acc = __builtin_amdgcn_mfma_i32_16x16x64_i8(af[u], bf[u], acc, 0, 0, 0);
  }
  if (l16 < ROWS) {
    float sw = smax[l16];
    #pragma unroll
    for (int r = 0; r < 4; r++) {
      int m = wave * 16 + quad * 4 + r;   // C/D: col=lane&15, row=quad*4+reg (m89)
      Cout[(size_t)m * N + n0 + l16] = (float)acc[r] * sA[m] * sw;
    }
  }
}

// ---------- ky: SSM contraction with folded kmid quant/coef work ----------
// grid (NH/2, B_): each block computes scale once, handles 2 heads (64KB state).
__global__ __launch_bounds__(256) void kyf(const float* __restrict__ state,
                                           const float* __restrict__ zxb,
                                           const float* __restrict__ dt_bias,
                                           const float* __restrict__ A_log,
                                           float* __restrict__ yraw) {
  __shared__ float sm[4];
  int hx = blockIdx.x, b = blockIdx.y, t = threadIdx.x;
  int lane = t & 63;
  const float* prow = zxb + (size_t)b * DPROJ;
  const float4* p4 = (const float4*)prow;
  // xBC absmax: f4 idx [1024, 2112) -- bit-identical to kmid's (max is
  // order-independent)
  float m = 0.f;
  #pragma unroll
  for (int i = 0; i < 5; i++) {
    int idx = 1024 + t + i * 256;
    if (idx < 2112) m = fmaxf(m, absmax4(p4[idx]));
  }
  float mx = blockMax256(m, sm);
  float s = mx * (1.0f / 127.0f);
  float rs = (s == 0.f) ? 0.f : 127.0f / mx;
  if (s == 0.f) s = 1.f;
  // quantized C fragment for this lane (C = f4 idx [2080, 2112))
  float4 craw = p4[2080 + (t & 31)];
  float4 c4;
  c4.x = rintf(craw.x * rs) * s;
  c4.y = rintf(craw.y * rs) * s;
  c4.z = rintf(craw.z * rs) * s;
  c4.w = rintf(craw.w * rs) * s;
  // sbc = Bq . Cq (lanes 0..31, butterfly identical to kmid's)
  float p = 0.f;
  if (lane < 32) {
    float4 braw = p4[2048 + lane];
    float4 bq;
    bq.x = rintf(braw.x * rs) * s;
    bq.y = rintf(braw.y * rs) * s;
    bq.z = rintf(braw.z * rs) * s;
    bq.w = rintf(braw.w * rs) * s;
    p = bq.x * c4.x + bq.y * c4.y + bq.z * c4.z + bq.w * c4.w;
  }
  #pragma unroll
  for (int off = 1; off < 32; off <<= 1) p += __shfl_xor(p, off, 64);
  float sbc = __shfl(p, 0, 64);
  #pragma unroll
  for (int hh = 0; hh < 2; hh++) {
    int h = hx * 2 + hh;
    // coef (identical formulas to kmid)
    float dtv = prow[2 * DSSM + 2 * DSTATE + h] + dt_bias[h];
    if (dtv < -2.f) dtv = 0.f;
    else if (dtv <= 2.f)
      dtv = 0.6931471805599453f + 0.5f * dtv + dtv * dtv * (1.f / 8.f)
            + dtv * dtv * dtv * (1.f / 48.f);
    float A = -expf(A_log[h]);
    float dA = fmaxf(dtv * A, -10000.f);
    float e = 1.f + dA + dA * dA * (1.f / 2.f) + dA * dA * dA * (1.f / 6.f)
              + dA * dA * dA * dA * (1.f / 24.f)
              + dA * dA * dA * dA * dA * (1.f / 120.f);
    e = fminf(fmaxf(e, 0.f), 1.f);
    float coef = dtv * sbc;
    const f4v* st = (const f4v*)(state + ((size_t)b * NH + h) * (HD * DSTATE));
    f4v s4[8];
    #pragma unroll
    for (int j = 0; j < 8; j++) s4[j] = __builtin_nontemporal_load(&st[j * 256 + t]);
    float acc[8];
    #pragma unroll
    for (int j = 0; j < 8; j++)
      acc[j] = s4[j].x * c4.x + s4[j].y * c4.y + s4[j].z * c4.z + s4[j].w * c4.w;
    #pragma unroll
    for (int off = 1; off < 32; off <<= 1) {
      #pragma unroll
      for (int j = 0; j < 8; j++) acc[j] += __shfl_xor(acc[j], off, 64);
    }
    if ((t & 31) == 0) {
      #pragma unroll
      for (int j = 0; j < 8; j++) {
        int r = j * 8 + (t >> 5);
        int d = h * HD + r;
        float xr = prow[DSSM + d];            // raw x; quantize on the fly
        float xq = rintf(xr * rs) * s;
        yraw[(size_t)b * DSSM + d] = e * acc[j] + coef * xq;
      }
    }
  }
}

// ---------- epilogue with folded x-quant: fq(y) -> +D*x -> *relu(z) -> fq ----
__global__ __launch_bounds__(256) void kepif(const float* __restrict__ yraw,
                                             const float* __restrict__ zxb,
                                             const float* __restrict__ Dv,
                                             unsigned int* __restrict__ q3,
                                             float* __restrict__ sy) {
  __shared__ float sm[4];
  int b = blockIdx.x, t = threadIdx.x;
  const float4* p4 = (const float4*)(zxb + (size_t)b * DPROJ);
  // xBC absmax (same deterministic scan as kyf/kmid)
  float mq = 0.f;
  #pragma unroll
  for (int i = 0; i < 5; i++) {
    int idx = 1024 + t + i * 256;
    if (idx < 2112) mq = fmaxf(mq, absmax4(p4[idx]));
  }
  float mxq = blockMax256(mq, sm);
  float sq = mxq * (1.0f / 127.0f);
  float rsq = (sq == 0.f) ? 0.f : 127.0f / mxq;
  if (sq == 0.f) sq = 1.f;
  const float* yrow = yraw + (size_t)b * DSSM;
  float4 yv[4];
  float m = 0.f;
  #pragma unroll
  for (int i = 0; i < 4; i++) {
    yv[i] = *(const float4*)(yrow + t * 4 + i * 1024);
    m = fmaxf(m, absmax4(yv[i]));
  }
  float mx1 = blockMax256(m, sm);
  float s1 = mx1 * (1.0f / 127.0f);
  float rs1 = (s1 == 0.f) ? 0.f : 127.0f / mx1;
  if (s1 == 0.f) s1 = 1.f;
  float4 y3[4];
  float m2 = 0.f;
  #pragma unroll
  for (int i = 0; i < 4; i++) {
    int fi = t + i * 256;                     // f4 idx within DSSM
    float4 xr = p4[1024 + fi];                // raw x from zxb
    float4 x4;
    x4.x = rintf(xr.x * rsq) * sq;
    x4.y = rintf(xr.y * rsq) * sq;
    x4.z = rintf(xr.z * rsq) * sq;
    x4.w = rintf(xr.w * rsq) * sq;
    float4 z4 = p4[fi];                       // raw z from zxb
    float4 d4 = ((const float4*)Dv)[fi];
    float4 r;
    r.x = (rintf(yv[i].x * rs1) * s1 + d4.x * x4.x) * fmaxf(z4.x, 0.f);
    r.y = (rintf(yv[i].y * rs1) * s1 + d4.y * x4.y) * fmaxf(z4.y, 0.f);
    r.z = (rintf(yv[i].z * rs1) * s1 + d4.z * x4.z) * fmaxf(z4.z, 0.f);
    r.w = (rintf(yv[i].w * rs1) * s1 + d4.w * x4.w) * fmaxf(z4.w, 0.f);
    y3[i] = r;
    m2 = fmaxf(m2, absmax4(r));
  }
  float mx3 = blockMax256(m2, sm);
  float s3 = mx3 * (1.0f / 127.0f);
  float rs3 = (s3 == 0.f) ? 0.f : 127.0f / mx3;
  if (s3 == 0.f) s3 = 1.f;
  if (t == 0) sy[b] = s3;
  unsigned int* orow = q3 + (size_t)b * (DSSM / 4);
  #pragma unroll
  for (int i = 0; i < 4; i++)
    orow[t + i * 256] = pack4(y3[i].x, y3[i].y, y3[i].z, y3[i].w, rs3);
}

extern "C" void kernel_launch(void* const* d_in, const int* in_sizes, int n_in,
                              void* d_out, int out_size, void* d_ws, size_t ws_size,
                              hipStream_t stream) {
  const float* hidden  = (const float*)d_in[0];
  const float* ssm     = (const float*)d_in[1];
  const float* W_in    = (const float*)d_in[2];
  const float* dt_bias = (const float*)d_in[3];
  const float* A_log   = (const float*)d_in[4];
  const float* Dv      = (const float*)d_in[5];
  const float* W_out   = (const float*)d_in[6];
  float* out = (float*)d_out;

  char* p = (char*)d_ws;
  auto alloc = [&](size_t bytes) {
    char* r = p;
    p += (bytes + 255) & ~(size_t)255;
    return r;
  };
  unsigned int* xq = (unsigned int*)alloc((size_t)B_ * DMODEL);
  unsigned int* q3 = (unsigned int*)alloc((size_t)B_ * DSSM);
  float* sx    = (float*)alloc(B_ * 4);
  float* sy    = (float*)alloc(B_ * 4);
  float* zxb   = (float*)alloc((size_t)B_ * DPROJ * 4);    // 2.2 MB
  float* yraw  = (float*)alloc((size_t)B_ * DSSM * 4);

  quantx<<<B_, 256, 0, stream>>>(hidden, xq, sx);
  fgemm<DMODEL, 16><<<DPROJ / 16, 256, 0, stream>>>(W_in, (const char*)xq, sx,
                                                    zxb, DPROJ);
  kyf<<<dim3(NH / 2, B_), 256, 0, stream>>>(ssm, zxb, dt_bias, A_log, yraw);
  kepif<<<B_, 256, 0, stream>>>(yraw, zxb, Dv, q3, sy);
  fgemm<DSSM, 4><<<DMODEL / 4, 256, 0, stream>>>(W_out, (const char*)q3, sy,
                                                 out, DMODEL);
}